// Round 13
// baseline (645.302 us; speedup 1.0000x reference)
//
#include <hip/hip_runtime.h>
#include <stdint.h>

#define NN    50000
#define INC   128
#define HIDC  256
#define OUTC  40
#define GCH   128
#define NL    4
#define NG    2
#define NEDGE 600000
#define EPSV  1e-5f

typedef __bf16 bf16x8 __attribute__((ext_vector_type(8)));
typedef float  f32x4  __attribute__((ext_vector_type(4)));
typedef unsigned short u16x4 __attribute__((ext_vector_type(4)));
typedef unsigned short u16x8 __attribute__((ext_vector_type(8)));

__device__ __forceinline__ float bf2f(unsigned short u) {
    union { float f; unsigned int i; } v;
    v.i = ((unsigned int)u) << 16;
    return v.f;
}
__device__ __forceinline__ unsigned short f2bf(float f) {
    union { float f; unsigned int i; } v;
    v.f = f;
    unsigned int u = v.i;
    u += 0x7FFFu + ((u >> 16) & 1u);   // RNE
    return (unsigned short)(u >> 16);
}
__device__ __forceinline__ float ldf(const void* p, int is_f32, long long i) {
    if (is_f32) return ((const float*)p)[i];
    return bf2f(((const unsigned short*)p)[i]);
}
__device__ __forceinline__ bf16x8 ld8(const unsigned short* p) {
    return *(const bf16x8*)p;
}

// ---- diagnostic marker ----
__global__ void k_marker(void* out, float val, int n) {
    int i = blockIdx.x * 256 + threadIdx.x;
    if (i < n) ((unsigned short*)out)[i] = f2bf(val);
}

// ---- zero deg + detect dtypes (proven) ----
__global__ void k_detect(const int* ei, const unsigned short* xprobe,
                         int* flags, int* deg) {
    int t = threadIdx.x;
    int gid = blockIdx.x * 256 + t;
    if (gid < NN) deg[gid] = 0;
    if (blockIdx.x == 0) {
        __shared__ int hi_or;
        __shared__ int wild_cnt;
        if (t == 0) { hi_or = 0; wild_cnt = 0; }
        __syncthreads();
        int acc = 0;
        for (int i = 0; i < 8; i++) acc |= ei[2 * (t + i * 256) + 1];
        if (acc) atomicOr(&hi_or, 1);
        int wild = 0;
        for (int i = 0; i < 2; i++) {
            unsigned short u = xprobe[t + i * 256];
            int e = (u >> 7) & 0xFF;
            if (e <= 0x30 || e >= 0xC0) wild++;
        }
        atomicAdd(&wild_cnt, wild);
        __syncthreads();
        if (t == 0) {
            flags[0] = hi_or ? 0 : 1;           // 1 => int64 edge_index
            flags[1] = (wild_cnt > 32) ? 1 : 0; // 1 => fp32 float tensors
        }
    }
}

// ---- one-time convert ----
#define CVT_X   6400000
#define CVT_W1  32768
#define CVT_CW  131072
#define CVT_W2  12288
#define CVT_TOT (CVT_X + CVT_W1 + CVT_CW + CVT_W2)

__global__ void k_convert(const void* x, const void* w1, const void* cw, const void* w2,
                          const int* flags,
                          unsigned short* xb, unsigned short* w1t,
                          unsigned short* cwt, unsigned short* w2t) {
    long long idx = (long long)blockIdx.x * 256 + threadIdx.x;
    if (idx >= CVT_TOT) return;
    int f32 = flags[1];
    if (idx < CVT_X) {
        xb[idx] = f2bf(ldf(x, f32, idx));
    } else if (idx < CVT_X + CVT_W1) {
        long long j = idx - CVT_X;
        int n = (int)(j >> 7), k = (int)(j & 127);
        w1t[j] = f2bf(ldf(w1, f32, (long long)k * HIDC + n));
    } else if (idx < CVT_X + CVT_W1 + CVT_CW) {
        long long j = idx - (CVT_X + CVT_W1);
        int lg = (int)(j >> 14);
        int rem = (int)(j & 16383);
        int n = rem >> 7, k = rem & 127;
        cwt[j] = f2bf(ldf(cw, f32, (long long)lg * GCH * GCH + (long long)k * GCH + n));
    } else {
        long long j = idx - (CVT_X + CVT_W1 + CVT_CW);
        int n = (int)(j >> 8), k = (int)(j & 255);
        w2t[j] = (n < OUTC) ? f2bf(ldf(w2, f32, (long long)k * OUTC + n)) : (unsigned short)0;
    }
}

__global__ void k_convert2(const void* b1, const void* ng, const void* nb, const void* cb,
                           const void* fg, const void* fb, const void* b2,
                           const int* flags,
                           float* b1f, float* ngf, float* nbf, float* cbf,
                           float* fgf, float* fbf, float* b2f) {
    int t = threadIdx.x;
    int f32 = flags[1];
    b1f[t] = ldf(b1, f32, t);
    fgf[t] = ldf(fg, f32, t);
    fbf[t] = ldf(fb, f32, t);
    if (t < 48) b2f[t] = (t < OUTC) ? ldf(b2, f32, t) : 0.0f;
    for (int i = 0; i < 4; i++) {
        int j = t + i * 256;
        ngf[j] = ldf(ng, f32, j);
        nbf[j] = ldf(nb, f32, j);
        cbf[j] = ldf(cb, f32, j);
    }
}

// ---- lin1: h = xb @ W1 + b1 ----
__global__ __launch_bounds__(256) void k_lin1(
    const unsigned short* __restrict__ xb,
    const unsigned short* __restrict__ w1t,
    const float* __restrict__ b1f,
    float* __restrict__ h)
{
    int bx = blockIdx.x;
    int r0 = (bx >> 1) * 128;
    int n0 = (bx & 1) * 128;
    int w = threadIdx.x >> 6, lane = threadIdx.x & 63;
    int quad = lane >> 4, ln = lane & 15;
    const f32x4 zf = {0.f, 0.f, 0.f, 0.f};
    const bf16x8 zb = {0, 0, 0, 0, 0, 0, 0, 0};
    f32x4 acc[2][8];
#pragma unroll
    for (int i = 0; i < 2; i++)
#pragma unroll
        for (int j = 0; j < 8; j++) acc[i][j] = zf;

#pragma unroll
    for (int kk = 0; kk < 4; kk++) {
        int ko = kk * 32 + quad * 8;
        bf16x8 a0, a1;
        {
            int r = r0 + w * 32 + ln;
            a0 = (r < NN) ? ld8(xb + (long long)r * INC + ko) : zb;
            r += 16;
            a1 = (r < NN) ? ld8(xb + (long long)r * INC + ko) : zb;
        }
#pragma unroll
        for (int nf = 0; nf < 8; nf++) {
            bf16x8 b = ld8(w1t + (long long)(n0 + nf * 16 + ln) * INC + ko);
            acc[0][nf] = __builtin_amdgcn_mfma_f32_16x16x32_bf16(a0, b, acc[0][nf], 0, 0, 0);
            acc[1][nf] = __builtin_amdgcn_mfma_f32_16x16x32_bf16(a1, b, acc[1][nf], 0, 0, 0);
        }
    }
#pragma unroll
    for (int mi = 0; mi < 2; mi++)
#pragma unroll
        for (int nf = 0; nf < 8; nf++) {
            int col = n0 + nf * 16 + ln;
            float bias = b1f[col];
#pragma unroll
            for (int r4 = 0; r4 < 4; r4++) {
                int row = r0 + w * 32 + mi * 16 + quad * 4 + r4;
                if (row < NN) h[(long long)row * HIDC + col] = acc[mi][nf][r4] + bias;
            }
        }
}

// ---- fused LN+ReLU+GEMM, 128-row tiles, COALESCED z epilogue via LDS repack ----
#define TSTR 152   // u16 stride for A tile
#define OSTR 136   // u16 stride for output repack tile (128x136 u16 = 34816B <= A tile)
__global__ __launch_bounds__(256) void k_ln_gemm(
    const float* __restrict__ h,
    const unsigned short* __restrict__ cw,
    const float* __restrict__ ga,
    const float* __restrict__ be,
    int in_half,
    unsigned short* __restrict__ z)
{
    __shared__ __align__(16) unsigned short a_tile[128 * TSTR];
    int t = threadIdx.x;
    int r0 = blockIdx.x * 128;

    int row = t >> 1, hh = t & 1;
    int r = r0 + row;
    const float* hp = h + (long long)r * HIDC + in_half * GCH + hh * 64;

    float sum = 0.f, sq = 0.f;
    float vbuf[64];
    if (r < NN) {
#pragma unroll
        for (int i = 0; i < 16; i++) {
            f32x4 v = *(const f32x4*)(hp + i * 4);
#pragma unroll
            for (int j = 0; j < 4; j++) {
                vbuf[i * 4 + j] = v[j];
                sum += v[j];
                sq += v[j] * v[j];
            }
        }
    } else {
#pragma unroll
        for (int i = 0; i < 64; i++) vbuf[i] = 0.f;
    }
    sum += __shfl_xor(sum, 1, 64);
    sq  += __shfl_xor(sq, 1, 64);
    float mu = sum * (1.0f / GCH);
    float var = sq * (1.0f / GCH) - mu * mu;
    float rs = rsqrtf(var + EPSV);

#pragma unroll
    for (int i = 0; i < 16; i++) {
        int c = hh * 64 + i * 4;
        u16x4 o;
#pragma unroll
        for (int j = 0; j < 4; j++) {
            float val = (vbuf[i * 4 + j] - mu) * rs * ga[c + j] + be[c + j];
            if (val < 0.f) val = 0.f;
            o[j] = f2bf(val);
        }
        *(u16x4*)(&a_tile[row * TSTR + c]) = o;
    }
    __syncthreads();

    int w = t >> 6, lane = t & 63;
    int quad = lane >> 4, ln = lane & 15;
    const f32x4 zf = {0.f, 0.f, 0.f, 0.f};
    f32x4 acc[2][8];
#pragma unroll
    for (int i = 0; i < 2; i++)
#pragma unroll
        for (int j = 0; j < 8; j++) acc[i][j] = zf;

#pragma unroll
    for (int kk = 0; kk < 4; kk++) {
        int ko = kk * 32 + quad * 8;
        bf16x8 a0 = *(const bf16x8*)(&a_tile[(w * 32 + ln) * TSTR + ko]);
        bf16x8 a1 = *(const bf16x8*)(&a_tile[(w * 32 + 16 + ln) * TSTR + ko]);
#pragma unroll
        for (int nf = 0; nf < 8; nf++) {
            bf16x8 b = ld8(cw + (long long)(nf * 16 + ln) * GCH + ko);
            acc[0][nf] = __builtin_amdgcn_mfma_f32_16x16x32_bf16(a0, b, acc[0][nf], 0, 0, 0);
            acc[1][nf] = __builtin_amdgcn_mfma_f32_16x16x32_bf16(a1, b, acc[1][nf], 0, 0, 0);
        }
    }

    // repack through LDS: scatter 2B results, then coalesced 16B stores
    __syncthreads();   // all A-tile reads complete; reuse as output tile
#pragma unroll
    for (int mi = 0; mi < 2; mi++)
#pragma unroll
        for (int nf = 0; nf < 8; nf++) {
            int col = nf * 16 + ln;
#pragma unroll
            for (int r4 = 0; r4 < 4; r4++) {
                int lrow = w * 32 + mi * 16 + quad * 4 + r4;
                a_tile[lrow * OSTR + col] = f2bf(acc[mi][nf][r4]);
            }
        }
    __syncthreads();

    // thread t: row = t>>1, 64 cols at (t&1)*64 -> 8x16B contiguous stores
    {
        int orow = t >> 1, ocol = (t & 1) * 64;
        int gr = r0 + orow;
        if (gr < NN) {
            const u16x8* src = (const u16x8*)(&a_tile[orow * OSTR + ocol]);
            u16x8* dst = (u16x8*)(z + (long long)gr * GCH + ocol);
#pragma unroll
            for (int i = 0; i < 8; i++) dst[i] = src[i];
        }
    }
}

// ---- CSR build ----
__global__ void k_count(const int* __restrict__ ei, const int* __restrict__ flags,
                        int* __restrict__ deg) {
    int e = (blockIdx.x * 256 + threadIdx.x) * 2;
    if (e >= NEDGE) return;
    int d0, d1;
    if (flags[0]) {
        int4 v = *(const int4*)(ei + 2 * (NEDGE + e));
        d0 = v.x; d1 = v.z;
    } else {
        int2 v = *(const int2*)(ei + NEDGE + e);
        d0 = v.x; d1 = v.y;
    }
    atomicAdd(&deg[d0], 1);
    if (e + 1 < NEDGE) atomicAdd(&deg[d1], 1);
}

#define SCAN_B 49
__global__ void k_scan_a(const int* __restrict__ deg, int* __restrict__ bsum) {
    __shared__ int part[256];
    int b = blockIdx.x, t = threadIdx.x;
    int base = b * 1024 + t * 4;
    int s = 0;
#pragma unroll
    for (int j = 0; j < 4; j++) {
        int i = base + j;
        if (i < NN) s += deg[i];
    }
    part[t] = s;
    __syncthreads();
    for (int off = 128; off > 0; off >>= 1) {
        if (t < off) part[t] += part[t + off];
        __syncthreads();
    }
    if (t == 0) bsum[b] = part[0];
}

__global__ void k_scan_b(const int* __restrict__ bsum, int* __restrict__ boff) {
    if (threadIdx.x == 0) {
        int run = 0;
        for (int i = 0; i < SCAN_B; i++) { boff[i] = run; run += bsum[i]; }
    }
}

__global__ void k_scan_c(const int* __restrict__ deg, const int* __restrict__ boff,
                         int* __restrict__ rowptr, int* __restrict__ cursor) {
    __shared__ int part[256];
    int b = blockIdx.x, t = threadIdx.x;
    int base = b * 1024 + t * 4;
    int v[4];
    int s = 0;
#pragma unroll
    for (int j = 0; j < 4; j++) {
        int i = base + j;
        v[j] = (i < NN) ? deg[i] : 0;
        s += v[j];
    }
    part[t] = s;
    __syncthreads();
    for (int off = 1; off < 256; off <<= 1) {
        int x = (t >= off) ? part[t - off] : 0;
        __syncthreads();
        part[t] += x;
        __syncthreads();
    }
    int run = boff[b] + part[t] - s;
#pragma unroll
    for (int j = 0; j < 4; j++) {
        int i = base + j;
        if (i < NN) { rowptr[i] = run; cursor[i] = run; }
        run += v[j];
    }
    if (b == SCAN_B - 1 && t == 255) rowptr[NN] = NEDGE;
}

// packed fill: ONE 4B store per edge — (bf16 weight << 16) | src (src < 65536)
__global__ void k_fill(const int* __restrict__ ei, const void* __restrict__ ew,
                       const int* __restrict__ flags,
                       int* __restrict__ cursor, unsigned int* __restrict__ epk) {
    int e = (blockIdx.x * 256 + threadIdx.x) * 2;
    if (e >= NEDGE) return;
    int is64 = flags[0];
    int f32 = flags[1];
    int d0, s0, d1 = 0, s1 = 0;
    int has1 = (e + 1 < NEDGE);
    if (is64) {
        d0 = ei[2 * (NEDGE + e)];
        s0 = ei[2 * e];
        if (has1) { d1 = ei[2 * (NEDGE + e) + 2]; s1 = ei[2 * e + 2]; }
    } else {
        d0 = ei[NEDGE + e];
        s0 = ei[e];
        if (has1) { d1 = ei[NEDGE + e + 1]; s1 = ei[e + 1]; }
    }
    int p0 = atomicAdd(&cursor[d0], 1);
    int p1 = has1 ? atomicAdd(&cursor[d1], 1) : 0;
    unsigned int w0 = f2bf(ldf(ew, f32, e));
    epk[p0] = (w0 << 16) | (unsigned int)s0;
    if (has1) {
        unsigned int w1 = f2bf(ldf(ew, f32, e + 1));
        epk[p1] = (w1 << 16) | (unsigned int)s1;
    }
}

// ---- aggregate: 16 thr/node x u16x8, 8-edge unroll, packed edge stream ----
__global__ __launch_bounds__(256) void k_agg(
    const int* __restrict__ rowptr, const unsigned int* __restrict__ epk,
    const unsigned short* __restrict__ z,
    const float* __restrict__ cb,
    float* __restrict__ h, int out_half)
{
    int node = blockIdx.x * 16 + (threadIdx.x >> 4);
    if (node >= NN) return;
    int c8 = (threadIdx.x & 15) << 3;   // 8 channels/thread
    int beg = rowptr[node], end = rowptr[node + 1];
    const unsigned short* zb = z + c8;
    float acc[8];
#pragma unroll
    for (int j = 0; j < 8; j++) acc[j] = 0.f;

    int e = beg;
    for (; e + 7 < end; e += 8) {
        unsigned int pe[8];
        u16x8 v[8];
#pragma unroll
        for (int i = 0; i < 8; i++) pe[i] = epk[e + i];
#pragma unroll
        for (int i = 0; i < 8; i++)
            v[i] = *(const u16x8*)(zb + (long long)(pe[i] & 0xFFFFu) * GCH);
#pragma unroll
        for (int i = 0; i < 8; i++) {
            float w = bf2f((unsigned short)(pe[i] >> 16));
#pragma unroll
            for (int j = 0; j < 8; j++) acc[j] += w * bf2f(v[i][j]);
        }
    }
    if (e + 3 < end) {
        unsigned int pe[4];
        u16x8 v[4];
#pragma unroll
        for (int i = 0; i < 4; i++) pe[i] = epk[e + i];
#pragma unroll
        for (int i = 0; i < 4; i++)
            v[i] = *(const u16x8*)(zb + (long long)(pe[i] & 0xFFFFu) * GCH);
#pragma unroll
        for (int i = 0; i < 4; i++) {
            float w = bf2f((unsigned short)(pe[i] >> 16));
#pragma unroll
            for (int j = 0; j < 8; j++) acc[j] += w * bf2f(v[i][j]);
        }
        e += 4;
    }
    for (; e < end; e++) {
        unsigned int pe = epk[e];
        float w0 = bf2f((unsigned short)(pe >> 16));
        u16x8 v = *(const u16x8*)(zb + (long long)(pe & 0xFFFFu) * GCH);
#pragma unroll
        for (int j = 0; j < 8; j++) acc[j] += w0 * bf2f(v[j]);
    }

    float* hp = h + (long long)node * HIDC + out_half * GCH + c8;
    f32x4 v0 = *(f32x4*)hp;
    f32x4 v1 = *(f32x4*)(hp + 4);
#pragma unroll
    for (int j = 0; j < 4; j++) {
        v0[j] += acc[j] + cb[c8 + j];
        v1[j] += acc[4 + j] + cb[c8 + 4 + j];
    }
    *(f32x4*)hp = v0;
    *(f32x4*)(hp + 4) = v1;
}

// ---- final: out = relu(LN256(h)) @ W2 + b2 (R5-proven) ----
#define FSTR 280
__global__ __launch_bounds__(256) void k_final(
    const float* __restrict__ h,
    const unsigned short* __restrict__ w2t,
    const float* __restrict__ fgf, const float* __restrict__ fbf,
    const float* __restrict__ b2f,
    const int* __restrict__ flags,
    void* __restrict__ out)
{
    __shared__ __align__(16) unsigned short a_tile[64 * FSTR];
    int t = threadIdx.x;
    int r0 = blockIdx.x * 64;

    int row = t >> 2, q = t & 3;
    int r = r0 + row;
    const float* hp = h + (long long)r * HIDC + q * 64;
    float sum = 0.f, sq = 0.f;
    float vbuf[64];
    if (r < NN) {
#pragma unroll
        for (int i = 0; i < 16; i++) {
            f32x4 v = *(const f32x4*)(hp + i * 4);
#pragma unroll
            for (int j = 0; j < 4; j++) {
                vbuf[i * 4 + j] = v[j];
                sum += v[j];
                sq += v[j] * v[j];
            }
        }
    } else {
#pragma unroll
        for (int i = 0; i < 64; i++) vbuf[i] = 0.f;
    }
    sum += __shfl_xor(sum, 1, 64);
    sum += __shfl_xor(sum, 2, 64);
    sq  += __shfl_xor(sq, 1, 64);
    sq  += __shfl_xor(sq, 2, 64);
    float mu = sum * (1.0f / HIDC);
    float var = sq * (1.0f / HIDC) - mu * mu;
    float rs = rsqrtf(var + EPSV);

#pragma unroll
    for (int i = 0; i < 16; i++) {
        int c = q * 64 + i * 4;
        u16x4 o;
#pragma unroll
        for (int j = 0; j < 4; j++) {
            float val = (vbuf[i * 4 + j] - mu) * rs * fgf[c + j] + fbf[c + j];
            if (val < 0.f) val = 0.f;
            o[j] = f2bf(val);
        }
        *(u16x4*)(&a_tile[row * FSTR + c]) = o;
    }
    __syncthreads();

    int w = t >> 6, lane = t & 63;
    int quad = lane >> 4, ln = lane & 15;
    const f32x4 zf = {0.f, 0.f, 0.f, 0.f};
    f32x4 acc[3];
#pragma unroll
    for (int j = 0; j < 3; j++) acc[j] = zf;
#pragma unroll
    for (int kk = 0; kk < 8; kk++) {
        int ko = kk * 32 + quad * 8;
        bf16x8 a = *(const bf16x8*)(&a_tile[(w * 16 + ln) * FSTR + ko]);
#pragma unroll
        for (int nf = 0; nf < 3; nf++) {
            bf16x8 b = ld8(w2t + (long long)(nf * 16 + ln) * HIDC + ko);
            acc[nf] = __builtin_amdgcn_mfma_f32_16x16x32_bf16(a, b, acc[nf], 0, 0, 0);
        }
    }
    int f32o = flags[1];
#pragma unroll
    for (int nf = 0; nf < 3; nf++) {
        int col = nf * 16 + ln;
        if (col >= OUTC) continue;
        float bias = b2f[col];
#pragma unroll
        for (int r4 = 0; r4 < 4; r4++) {
            int row2 = r0 + w * 16 + quad * 4 + r4;
            if (row2 < NN) {
                float val = acc[nf][r4] + bias;
                long long o = (long long)row2 * OUTC + col;
                if (f32o) ((float*)out)[o] = val;
                else      ((unsigned short*)out)[o] = f2bf(val);
            }
        }
    }
}

extern "C" void kernel_launch(void* const* d_in, const int* in_sizes, int n_in,
                              void* d_out, int out_size, void* d_ws, size_t ws_size,
                              hipStream_t stream)
{
    const void* x       = d_in[0];
    const int*  ei      = (const int*)d_in[1];
    const void* ew      = d_in[2];
    const void* lin1_w  = d_in[3];
    const void* lin1_b  = d_in[4];
    const void* lin2_w  = d_in[5];
    const void* lin2_b  = d_in[6];
    const void* norm_g  = d_in[7];
    const void* norm_b  = d_in[8];
    const void* conv_w  = d_in[9];
    const void* conv_b  = d_in[10];
    const void* fnorm_g = d_in[11];
    const void* fnorm_b = d_in[12];

    char* ws = (char*)d_ws;
    size_t off = 0;
    auto alloc = [&](size_t bytes) { void* p = (void*)(ws + off); off += (bytes + 255) & ~255ull; return p; };

    float*          h      = (float*)alloc((size_t)NN * HIDC * 4);
    unsigned short* z      = (unsigned short*)alloc((size_t)NN * GCH * 2);
    unsigned short* xb     = (unsigned short*)alloc((size_t)NN * INC * 2);
    unsigned short* w1t    = (unsigned short*)alloc((size_t)CVT_W1 * 2);
    unsigned short* cwt    = (unsigned short*)alloc((size_t)CVT_CW * 2);
    unsigned short* w2t    = (unsigned short*)alloc((size_t)CVT_W2 * 2);
    float*          b1f    = (float*)alloc(256 * 4);
    float*          ngf    = (float*)alloc(1024 * 4);
    float*          nbf    = (float*)alloc(1024 * 4);
    float*          cbf    = (float*)alloc(1024 * 4);
    float*          fgf    = (float*)alloc(256 * 4);
    float*          fbf    = (float*)alloc(256 * 4);
    float*          b2f    = (float*)alloc(48 * 4);
    int*            deg    = (int*)alloc((size_t)NN * 4);
    int*            rowptr = (int*)alloc(((size_t)NN + 1) * 4);
    int*            cursor = (int*)alloc((size_t)NN * 4);
    unsigned int*   epk    = (unsigned int*)alloc((size_t)NEDGE * 4);
    int*            flags  = (int*)alloc(256);
    int*            bsum   = (int*)alloc(SCAN_B * 4);
    int*            boff   = (int*)alloc(SCAN_B * 4);

    if (ws_size < off || n_in < 13) {
        float mv = 100.0f + (float)(ws_size >> 20) + ((n_in < 13) ? 10000.0f : 0.0f);
        k_marker<<<(out_size + 255) / 256, 256, 0, stream>>>(d_out, mv, out_size);
        return;
    }

    k_detect<<<196, 256, 0, stream>>>(ei, (const unsigned short*)x, flags, deg);
    k_convert<<<(CVT_TOT + 255) / 256, 256, 0, stream>>>(x, lin1_w, conv_w, lin2_w,
                                                         flags, xb, w1t, cwt, w2t);
    k_convert2<<<1, 256, 0, stream>>>(lin1_b, norm_g, norm_b, conv_b,
                                      fnorm_g, fnorm_b, lin2_b, flags,
                                      b1f, ngf, nbf, cbf, fgf, fbf, b2f);
    k_lin1<<<782, 256, 0, stream>>>(xb, w1t, b1f, h);

    k_count<<<(NEDGE / 2 + 255) / 256, 256, 0, stream>>>(ei, flags, deg);
    k_scan_a<<<SCAN_B, 256, 0, stream>>>(deg, bsum);
    k_scan_b<<<1, 64, 0, stream>>>(bsum, boff);
    k_scan_c<<<SCAN_B, 256, 0, stream>>>(deg, boff, rowptr, cursor);
    k_fill<<<(NEDGE / 2 + 255) / 256, 256, 0, stream>>>(ei, ew, flags, cursor, epk);

    const int AGG_B = (NN + 15) / 16;   // 3125
    for (int l = 0; l < NL; l++) {
        for (int g = 0; g < NG; g++) {
            int lg = l * NG + g;
            int in_half = g ^ 1;
            k_ln_gemm<<<391, 256, 0, stream>>>(h, cwt + (size_t)lg * GCH * GCH,
                                               ngf + lg * GCH, nbf + lg * GCH,
                                               in_half, z);
            k_agg<<<AGG_B, 256, 0, stream>>>(rowptr, epk, z,
                                             cbf + lg * GCH, h, g);
        }
    }
    k_final<<<782, 256, 0, stream>>>(h, w2t, fgf, fbf, b2f, flags, d_out);
}

// Round 14
// 620.280 us; speedup vs baseline: 1.0403x; 1.0403x over previous
//
#include <hip/hip_runtime.h>
#include <stdint.h>

#define NN    50000
#define INC   128
#define HIDC  256
#define OUTC  40
#define GCH   128
#define NL    4
#define NG    2
#define NEDGE 600000
#define EPSV  1e-5f

typedef __bf16 bf16x8 __attribute__((ext_vector_type(8)));
typedef float  f32x4  __attribute__((ext_vector_type(4)));
typedef unsigned short u16x4 __attribute__((ext_vector_type(4)));
typedef unsigned short u16x8 __attribute__((ext_vector_type(8)));

__device__ __forceinline__ float bf2f(unsigned short u) {
    union { float f; unsigned int i; } v;
    v.i = ((unsigned int)u) << 16;
    return v.f;
}
__device__ __forceinline__ unsigned short f2bf(float f) {
    union { float f; unsigned int i; } v;
    v.f = f;
    unsigned int u = v.i;
    u += 0x7FFFu + ((u >> 16) & 1u);   // RNE
    return (unsigned short)(u >> 16);
}
__device__ __forceinline__ float ldf(const void* p, int is_f32, long long i) {
    if (is_f32) return ((const float*)p)[i];
    return bf2f(((const unsigned short*)p)[i]);
}
__device__ __forceinline__ bf16x8 ld8(const unsigned short* p) {
    return *(const bf16x8*)p;
}

// ---- diagnostic marker ----
__global__ void k_marker(void* out, float val, int n) {
    int i = blockIdx.x * 256 + threadIdx.x;
    if (i < n) ((unsigned short*)out)[i] = f2bf(val);
}

// ---- zero deg + detect dtypes (proven) ----
__global__ void k_detect(const int* ei, const unsigned short* xprobe,
                         int* flags, int* deg) {
    int t = threadIdx.x;
    int gid = blockIdx.x * 256 + t;
    if (gid < NN) deg[gid] = 0;
    if (blockIdx.x == 0) {
        __shared__ int hi_or;
        __shared__ int wild_cnt;
        if (t == 0) { hi_or = 0; wild_cnt = 0; }
        __syncthreads();
        int acc = 0;
        for (int i = 0; i < 8; i++) acc |= ei[2 * (t + i * 256) + 1];
        if (acc) atomicOr(&hi_or, 1);
        int wild = 0;
        for (int i = 0; i < 2; i++) {
            unsigned short u = xprobe[t + i * 256];
            int e = (u >> 7) & 0xFF;
            if (e <= 0x30 || e >= 0xC0) wild++;
        }
        atomicAdd(&wild_cnt, wild);
        __syncthreads();
        if (t == 0) {
            flags[0] = hi_or ? 0 : 1;           // 1 => int64 edge_index
            flags[1] = (wild_cnt > 32) ? 1 : 0; // 1 => fp32 float tensors
        }
    }
}

// ---- one-time convert ----
#define CVT_X   6400000
#define CVT_W1  32768
#define CVT_CW  131072
#define CVT_W2  12288
#define CVT_TOT (CVT_X + CVT_W1 + CVT_CW + CVT_W2)

__global__ void k_convert(const void* x, const void* w1, const void* cw, const void* w2,
                          const int* flags,
                          unsigned short* xb, unsigned short* w1t,
                          unsigned short* cwt, unsigned short* w2t) {
    long long idx = (long long)blockIdx.x * 256 + threadIdx.x;
    if (idx >= CVT_TOT) return;
    int f32 = flags[1];
    if (idx < CVT_X) {
        xb[idx] = f2bf(ldf(x, f32, idx));
    } else if (idx < CVT_X + CVT_W1) {
        long long j = idx - CVT_X;
        int n = (int)(j >> 7), k = (int)(j & 127);
        w1t[j] = f2bf(ldf(w1, f32, (long long)k * HIDC + n));
    } else if (idx < CVT_X + CVT_W1 + CVT_CW) {
        long long j = idx - (CVT_X + CVT_W1);
        int lg = (int)(j >> 14);
        int rem = (int)(j & 16383);
        int n = rem >> 7, k = rem & 127;
        cwt[j] = f2bf(ldf(cw, f32, (long long)lg * GCH * GCH + (long long)k * GCH + n));
    } else {
        long long j = idx - (CVT_X + CVT_W1 + CVT_CW);
        int n = (int)(j >> 8), k = (int)(j & 255);
        w2t[j] = (n < OUTC) ? f2bf(ldf(w2, f32, (long long)k * OUTC + n)) : (unsigned short)0;
    }
}

__global__ void k_convert2(const void* b1, const void* ng, const void* nb, const void* cb,
                           const void* fg, const void* fb, const void* b2,
                           const int* flags,
                           float* b1f, float* ngf, float* nbf, float* cbf,
                           float* fgf, float* fbf, float* b2f) {
    int t = threadIdx.x;
    int f32 = flags[1];
    b1f[t] = ldf(b1, f32, t);
    fgf[t] = ldf(fg, f32, t);
    fbf[t] = ldf(fb, f32, t);
    if (t < 48) b2f[t] = (t < OUTC) ? ldf(b2, f32, t) : 0.0f;
    for (int i = 0; i < 4; i++) {
        int j = t + i * 256;
        ngf[j] = ldf(ng, f32, j);
        nbf[j] = ldf(nb, f32, j);
        cbf[j] = ldf(cb, f32, j);
    }
}

// ---- lin1: h = xb @ W1 + b1 (h stored bf16) ----
__global__ __launch_bounds__(256) void k_lin1(
    const unsigned short* __restrict__ xb,
    const unsigned short* __restrict__ w1t,
    const float* __restrict__ b1f,
    unsigned short* __restrict__ h)
{
    int bx = blockIdx.x;
    int r0 = (bx >> 1) * 128;
    int n0 = (bx & 1) * 128;
    int w = threadIdx.x >> 6, lane = threadIdx.x & 63;
    int quad = lane >> 4, ln = lane & 15;
    const f32x4 zf = {0.f, 0.f, 0.f, 0.f};
    const bf16x8 zb = {0, 0, 0, 0, 0, 0, 0, 0};
    f32x4 acc[2][8];
#pragma unroll
    for (int i = 0; i < 2; i++)
#pragma unroll
        for (int j = 0; j < 8; j++) acc[i][j] = zf;

#pragma unroll
    for (int kk = 0; kk < 4; kk++) {
        int ko = kk * 32 + quad * 8;
        bf16x8 a0, a1;
        {
            int r = r0 + w * 32 + ln;
            a0 = (r < NN) ? ld8(xb + (long long)r * INC + ko) : zb;
            r += 16;
            a1 = (r < NN) ? ld8(xb + (long long)r * INC + ko) : zb;
        }
#pragma unroll
        for (int nf = 0; nf < 8; nf++) {
            bf16x8 b = ld8(w1t + (long long)(n0 + nf * 16 + ln) * INC + ko);
            acc[0][nf] = __builtin_amdgcn_mfma_f32_16x16x32_bf16(a0, b, acc[0][nf], 0, 0, 0);
            acc[1][nf] = __builtin_amdgcn_mfma_f32_16x16x32_bf16(a1, b, acc[1][nf], 0, 0, 0);
        }
    }
#pragma unroll
    for (int mi = 0; mi < 2; mi++)
#pragma unroll
        for (int nf = 0; nf < 8; nf++) {
            int col = n0 + nf * 16 + ln;
            float bias = b1f[col];
#pragma unroll
            for (int r4 = 0; r4 < 4; r4++) {
                int row = r0 + w * 32 + mi * 16 + quad * 4 + r4;
                if (row < NN) h[(long long)row * HIDC + col] = f2bf(acc[mi][nf][r4] + bias);
            }
        }
}

// ---- fused LN+ReLU+GEMM (R12-proven, 128-row tiles, h bf16) ----
#define TSTR 152
__global__ __launch_bounds__(256) void k_ln_gemm(
    const unsigned short* __restrict__ h,
    const unsigned short* __restrict__ cw,
    const float* __restrict__ ga,
    const float* __restrict__ be,
    int in_half,
    unsigned short* __restrict__ z)
{
    __shared__ __align__(16) unsigned short a_tile[128 * TSTR];
    int t = threadIdx.x;
    int r0 = blockIdx.x * 128;

    int row = t >> 1, hh = t & 1;
    int r = r0 + row;
    const unsigned short* hp = h + (long long)r * HIDC + in_half * GCH + hh * 64;

    float sum = 0.f, sq = 0.f;
    float vbuf[64];
    if (r < NN) {
#pragma unroll
        for (int i = 0; i < 8; i++) {
            u16x8 v = *(const u16x8*)(hp + i * 8);
#pragma unroll
            for (int j = 0; j < 8; j++) {
                float f = bf2f(v[j]);
                vbuf[i * 8 + j] = f;
                sum += f;
                sq += f * f;
            }
        }
    } else {
#pragma unroll
        for (int i = 0; i < 64; i++) vbuf[i] = 0.f;
    }
    sum += __shfl_xor(sum, 1, 64);
    sq  += __shfl_xor(sq, 1, 64);
    float mu = sum * (1.0f / GCH);
    float var = sq * (1.0f / GCH) - mu * mu;
    float rs = rsqrtf(var + EPSV);

#pragma unroll
    for (int i = 0; i < 16; i++) {
        int c = hh * 64 + i * 4;
        u16x4 o;
#pragma unroll
        for (int j = 0; j < 4; j++) {
            float val = (vbuf[i * 4 + j] - mu) * rs * ga[c + j] + be[c + j];
            if (val < 0.f) val = 0.f;
            o[j] = f2bf(val);
        }
        *(u16x4*)(&a_tile[row * TSTR + c]) = o;
    }
    __syncthreads();

    int w = t >> 6, lane = t & 63;
    int quad = lane >> 4, ln = lane & 15;
    const f32x4 zf = {0.f, 0.f, 0.f, 0.f};
    f32x4 acc[2][8];
#pragma unroll
    for (int i = 0; i < 2; i++)
#pragma unroll
        for (int j = 0; j < 8; j++) acc[i][j] = zf;

#pragma unroll
    for (int kk = 0; kk < 4; kk++) {
        int ko = kk * 32 + quad * 8;
        bf16x8 a0 = *(const bf16x8*)(&a_tile[(w * 32 + ln) * TSTR + ko]);
        bf16x8 a1 = *(const bf16x8*)(&a_tile[(w * 32 + 16 + ln) * TSTR + ko]);
#pragma unroll
        for (int nf = 0; nf < 8; nf++) {
            bf16x8 b = ld8(cw + (long long)(nf * 16 + ln) * GCH + ko);
            acc[0][nf] = __builtin_amdgcn_mfma_f32_16x16x32_bf16(a0, b, acc[0][nf], 0, 0, 0);
            acc[1][nf] = __builtin_amdgcn_mfma_f32_16x16x32_bf16(a1, b, acc[1][nf], 0, 0, 0);
        }
    }
#pragma unroll
    for (int mi = 0; mi < 2; mi++)
#pragma unroll
        for (int nf = 0; nf < 8; nf++) {
            int col = nf * 16 + ln;
#pragma unroll
            for (int r4 = 0; r4 < 4; r4++) {
                int row2 = r0 + w * 32 + mi * 16 + quad * 4 + r4;
                if (row2 < NN) z[(long long)row2 * GCH + col] = f2bf(acc[mi][nf][r4]);
            }
        }
}

// ---- CSR build ----
__global__ void k_count(const int* __restrict__ ei, const int* __restrict__ flags,
                        int* __restrict__ deg) {
    int e = (blockIdx.x * 256 + threadIdx.x) * 2;
    if (e >= NEDGE) return;
    int d0, d1;
    if (flags[0]) {
        int4 v = *(const int4*)(ei + 2 * (NEDGE + e));
        d0 = v.x; d1 = v.z;
    } else {
        int2 v = *(const int2*)(ei + NEDGE + e);
        d0 = v.x; d1 = v.y;
    }
    atomicAdd(&deg[d0], 1);
    if (e + 1 < NEDGE) atomicAdd(&deg[d1], 1);
}

#define SCAN_B 49
__global__ void k_scan_a(const int* __restrict__ deg, int* __restrict__ bsum) {
    __shared__ int part[256];
    int b = blockIdx.x, t = threadIdx.x;
    int base = b * 1024 + t * 4;
    int s = 0;
#pragma unroll
    for (int j = 0; j < 4; j++) {
        int i = base + j;
        if (i < NN) s += deg[i];
    }
    part[t] = s;
    __syncthreads();
    for (int off = 128; off > 0; off >>= 1) {
        if (t < off) part[t] += part[t + off];
        __syncthreads();
    }
    if (t == 0) bsum[b] = part[0];
}

__global__ void k_scan_b(const int* __restrict__ bsum, int* __restrict__ boff) {
    if (threadIdx.x == 0) {
        int run = 0;
        for (int i = 0; i < SCAN_B; i++) { boff[i] = run; run += bsum[i]; }
    }
}

__global__ void k_scan_c(const int* __restrict__ deg, const int* __restrict__ boff,
                         int* __restrict__ rowptr, int* __restrict__ cursor) {
    __shared__ int part[256];
    int b = blockIdx.x, t = threadIdx.x;
    int base = b * 1024 + t * 4;
    int v[4];
    int s = 0;
#pragma unroll
    for (int j = 0; j < 4; j++) {
        int i = base + j;
        v[j] = (i < NN) ? deg[i] : 0;
        s += v[j];
    }
    part[t] = s;
    __syncthreads();
    for (int off = 1; off < 256; off <<= 1) {
        int x = (t >= off) ? part[t - off] : 0;
        __syncthreads();
        part[t] += x;
        __syncthreads();
    }
    int run = boff[b] + part[t] - s;
#pragma unroll
    for (int j = 0; j < 4; j++) {
        int i = base + j;
        if (i < NN) { rowptr[i] = run; cursor[i] = run; }
        run += v[j];
    }
    if (b == SCAN_B - 1 && t == 255) rowptr[NN] = NEDGE;
}

// packed fill: ONE 4B store per edge — (bf16 weight << 16) | src (src < 65536)
__global__ void k_fill(const int* __restrict__ ei, const void* __restrict__ ew,
                       const int* __restrict__ flags,
                       int* __restrict__ cursor, unsigned int* __restrict__ epk) {
    int e = (blockIdx.x * 256 + threadIdx.x) * 2;
    if (e >= NEDGE) return;
    int is64 = flags[0];
    int f32 = flags[1];
    int d0, s0, d1 = 0, s1 = 0;
    int has1 = (e + 1 < NEDGE);
    if (is64) {
        d0 = ei[2 * (NEDGE + e)];
        s0 = ei[2 * e];
        if (has1) { d1 = ei[2 * (NEDGE + e) + 2]; s1 = ei[2 * e + 2]; }
    } else {
        d0 = ei[NEDGE + e];
        s0 = ei[e];
        if (has1) { d1 = ei[NEDGE + e + 1]; s1 = ei[e + 1]; }
    }
    int p0 = atomicAdd(&cursor[d0], 1);
    int p1 = has1 ? atomicAdd(&cursor[d1], 1) : 0;
    unsigned int w0 = f2bf(ldf(ew, f32, e));
    epk[p0] = (w0 << 16) | (unsigned int)s0;
    if (has1) {
        unsigned int w1 = f2bf(ldf(ew, f32, e + 1));
        epk[p1] = (w1 << 16) | (unsigned int)s1;
    }
}

// ---- aggregate: 16 thr/node x u16x8, 8-edge unroll, packed edges, h bf16 RMW ----
__global__ __launch_bounds__(256) void k_agg(
    const int* __restrict__ rowptr, const unsigned int* __restrict__ epk,
    const unsigned short* __restrict__ z,
    const float* __restrict__ cb,
    unsigned short* __restrict__ h, int out_half)
{
    int node = blockIdx.x * 16 + (threadIdx.x >> 4);
    if (node >= NN) return;
    int c8 = (threadIdx.x & 15) << 3;   // 8 channels/thread
    int beg = rowptr[node], end = rowptr[node + 1];
    const unsigned short* zb = z + c8;
    float acc[8];
#pragma unroll
    for (int j = 0; j < 8; j++) acc[j] = 0.f;

    int e = beg;
    for (; e + 7 < end; e += 8) {
        unsigned int pe[8];
        u16x8 v[8];
#pragma unroll
        for (int i = 0; i < 8; i++) pe[i] = epk[e + i];
#pragma unroll
        for (int i = 0; i < 8; i++)
            v[i] = *(const u16x8*)(zb + (long long)(pe[i] & 0xFFFFu) * GCH);
#pragma unroll
        for (int i = 0; i < 8; i++) {
            float w = bf2f((unsigned short)(pe[i] >> 16));
#pragma unroll
            for (int j = 0; j < 8; j++) acc[j] += w * bf2f(v[i][j]);
        }
    }
    if (e + 3 < end) {
        unsigned int pe[4];
        u16x8 v[4];
#pragma unroll
        for (int i = 0; i < 4; i++) pe[i] = epk[e + i];
#pragma unroll
        for (int i = 0; i < 4; i++)
            v[i] = *(const u16x8*)(zb + (long long)(pe[i] & 0xFFFFu) * GCH);
#pragma unroll
        for (int i = 0; i < 4; i++) {
            float w = bf2f((unsigned short)(pe[i] >> 16));
#pragma unroll
            for (int j = 0; j < 8; j++) acc[j] += w * bf2f(v[i][j]);
        }
        e += 4;
    }
    for (; e < end; e++) {
        unsigned int pe = epk[e];
        float w0 = bf2f((unsigned short)(pe >> 16));
        u16x8 v = *(const u16x8*)(zb + (long long)(pe & 0xFFFFu) * GCH);
#pragma unroll
        for (int j = 0; j < 8; j++) acc[j] += w0 * bf2f(v[j]);
    }

    unsigned short* hp = h + (long long)node * HIDC + out_half * GCH + c8;
    u16x8 hv = *(u16x8*)hp;
#pragma unroll
    for (int j = 0; j < 8; j++)
        hv[j] = f2bf(bf2f(hv[j]) + acc[j] + cb[c8 + j]);
    *(u16x8*)hp = hv;
}

// ---- final: out = relu(LN256(h)) @ W2 + b2 (h bf16) ----
#define FSTR 280
__global__ __launch_bounds__(256) void k_final(
    const unsigned short* __restrict__ h,
    const unsigned short* __restrict__ w2t,
    const float* __restrict__ fgf, const float* __restrict__ fbf,
    const float* __restrict__ b2f,
    const int* __restrict__ flags,
    void* __restrict__ out)
{
    __shared__ __align__(16) unsigned short a_tile[64 * FSTR];
    int t = threadIdx.x;
    int r0 = blockIdx.x * 64;

    int row = t >> 2, q = t & 3;
    int r = r0 + row;
    const unsigned short* hp = h + (long long)r * HIDC + q * 64;
    float sum = 0.f, sq = 0.f;
    float vbuf[64];
    if (r < NN) {
#pragma unroll
        for (int i = 0; i < 8; i++) {
            u16x8 v = *(const u16x8*)(hp + i * 8);
#pragma unroll
            for (int j = 0; j < 8; j++) {
                float f = bf2f(v[j]);
                vbuf[i * 8 + j] = f;
                sum += f;
                sq += f * f;
            }
        }
    } else {
#pragma unroll
        for (int i = 0; i < 64; i++) vbuf[i] = 0.f;
    }
    sum += __shfl_xor(sum, 1, 64);
    sum += __shfl_xor(sum, 2, 64);
    sq  += __shfl_xor(sq, 1, 64);
    sq  += __shfl_xor(sq, 2, 64);
    float mu = sum * (1.0f / HIDC);
    float var = sq * (1.0f / HIDC) - mu * mu;
    float rs = rsqrtf(var + EPSV);

#pragma unroll
    for (int i = 0; i < 16; i++) {
        int c = q * 64 + i * 4;
        u16x4 o;
#pragma unroll
        for (int j = 0; j < 4; j++) {
            float val = (vbuf[i * 4 + j] - mu) * rs * fgf[c + j] + fbf[c + j];
            if (val < 0.f) val = 0.f;
            o[j] = f2bf(val);
        }
        *(u16x4*)(&a_tile[row * FSTR + c]) = o;
    }
    __syncthreads();

    int w = t >> 6, lane = t & 63;
    int quad = lane >> 4, ln = lane & 15;
    const f32x4 zf = {0.f, 0.f, 0.f, 0.f};
    f32x4 acc[3];
#pragma unroll
    for (int j = 0; j < 3; j++) acc[j] = zf;
#pragma unroll
    for (int kk = 0; kk < 8; kk++) {
        int ko = kk * 32 + quad * 8;
        bf16x8 a = *(const bf16x8*)(&a_tile[(w * 16 + ln) * FSTR + ko]);
#pragma unroll
        for (int nf = 0; nf < 3; nf++) {
            bf16x8 b = ld8(w2t + (long long)(nf * 16 + ln) * HIDC + ko);
            acc[nf] = __builtin_amdgcn_mfma_f32_16x16x32_bf16(a, b, acc[nf], 0, 0, 0);
        }
    }
    int f32o = flags[1];
#pragma unroll
    for (int nf = 0; nf < 3; nf++) {
        int col = nf * 16 + ln;
        if (col >= OUTC) continue;
        float bias = b2f[col];
#pragma unroll
        for (int r4 = 0; r4 < 4; r4++) {
            int row2 = r0 + w * 16 + quad * 4 + r4;
            if (row2 < NN) {
                float val = acc[nf][r4] + bias;
                long long o = (long long)row2 * OUTC + col;
                if (f32o) ((float*)out)[o] = val;
                else      ((unsigned short*)out)[o] = f2bf(val);
            }
        }
    }
}

extern "C" void kernel_launch(void* const* d_in, const int* in_sizes, int n_in,
                              void* d_out, int out_size, void* d_ws, size_t ws_size,
                              hipStream_t stream)
{
    const void* x       = d_in[0];
    const int*  ei      = (const int*)d_in[1];
    const void* ew      = d_in[2];
    const void* lin1_w  = d_in[3];
    const void* lin1_b  = d_in[4];
    const void* lin2_w  = d_in[5];
    const void* lin2_b  = d_in[6];
    const void* norm_g  = d_in[7];
    const void* norm_b  = d_in[8];
    const void* conv_w  = d_in[9];
    const void* conv_b  = d_in[10];
    const void* fnorm_g = d_in[11];
    const void* fnorm_b = d_in[12];

    char* ws = (char*)d_ws;
    size_t off = 0;
    auto alloc = [&](size_t bytes) { void* p = (void*)(ws + off); off += (bytes + 255) & ~255ull; return p; };

    unsigned short* h      = (unsigned short*)alloc((size_t)NN * HIDC * 2);
    unsigned short* z      = (unsigned short*)alloc((size_t)NN * GCH * 2);
    unsigned short* xb     = (unsigned short*)alloc((size_t)NN * INC * 2);
    unsigned short* w1t    = (unsigned short*)alloc((size_t)CVT_W1 * 2);
    unsigned short* cwt    = (unsigned short*)alloc((size_t)CVT_CW * 2);
    unsigned short* w2t    = (unsigned short*)alloc((size_t)CVT_W2 * 2);
    float*          b1f    = (float*)alloc(256 * 4);
    float*          ngf    = (float*)alloc(1024 * 4);
    float*          nbf    = (float*)alloc(1024 * 4);
    float*          cbf    = (float*)alloc(1024 * 4);
    float*          fgf    = (float*)alloc(256 * 4);
    float*          fbf    = (float*)alloc(256 * 4);
    float*          b2f    = (float*)alloc(48 * 4);
    int*            deg    = (int*)alloc((size_t)NN * 4);
    int*            rowptr = (int*)alloc(((size_t)NN + 1) * 4);
    int*            cursor = (int*)alloc((size_t)NN * 4);
    unsigned int*   epk    = (unsigned int*)alloc((size_t)NEDGE * 4);
    int*            flags  = (int*)alloc(256);
    int*            bsum   = (int*)alloc(SCAN_B * 4);
    int*            boff   = (int*)alloc(SCAN_B * 4);

    if (ws_size < off || n_in < 13) {
        float mv = 100.0f + (float)(ws_size >> 20) + ((n_in < 13) ? 10000.0f : 0.0f);
        k_marker<<<(out_size + 255) / 256, 256, 0, stream>>>(d_out, mv, out_size);
        return;
    }

    k_detect<<<196, 256, 0, stream>>>(ei, (const unsigned short*)x, flags, deg);
    k_convert<<<(CVT_TOT + 255) / 256, 256, 0, stream>>>(x, lin1_w, conv_w, lin2_w,
                                                         flags, xb, w1t, cwt, w2t);
    k_convert2<<<1, 256, 0, stream>>>(lin1_b, norm_g, norm_b, conv_b,
                                      fnorm_g, fnorm_b, lin2_b, flags,
                                      b1f, ngf, nbf, cbf, fgf, fbf, b2f);
    k_lin1<<<782, 256, 0, stream>>>(xb, w1t, b1f, h);

    k_count<<<(NEDGE / 2 + 255) / 256, 256, 0, stream>>>(ei, flags, deg);
    k_scan_a<<<SCAN_B, 256, 0, stream>>>(deg, bsum);
    k_scan_b<<<1, 64, 0, stream>>>(bsum, boff);
    k_scan_c<<<SCAN_B, 256, 0, stream>>>(deg, boff, rowptr, cursor);
    k_fill<<<(NEDGE / 2 + 255) / 256, 256, 0, stream>>>(ei, ew, flags, cursor, epk);

    const int AGG_B = (NN + 15) / 16;   // 3125
    for (int l = 0; l < NL; l++) {
        for (int g = 0; g < NG; g++) {
            int lg = l * NG + g;
            int in_half = g ^ 1;
            k_ln_gemm<<<391, 256, 0, stream>>>(h, cwt + (size_t)lg * GCH * GCH,
                                               ngf + lg * GCH, nbf + lg * GCH,
                                               in_half, z);
            k_agg<<<AGG_B, 256, 0, stream>>>(rowptr, epk, z,
                                             cbf + lg * GCH, h, g);
        }
    }
    k_final<<<782, 256, 0, stream>>>(h, w2t, fgf, fbf, b2f, flags, d_out);
}

// Round 15
// 615.860 us; speedup vs baseline: 1.0478x; 1.0072x over previous
//
#include <hip/hip_runtime.h>
#include <stdint.h>

#define NN    50000
#define INC   128
#define HIDC  256
#define OUTC  40
#define GCH   128
#define NL    4
#define NG    2
#define NEDGE 600000
#define EPSV  1e-5f

typedef __bf16 bf16x8 __attribute__((ext_vector_type(8)));
typedef float  f32x4  __attribute__((ext_vector_type(4)));
typedef unsigned short u16x4 __attribute__((ext_vector_type(4)));
typedef unsigned short u16x8 __attribute__((ext_vector_type(8)));

__device__ __forceinline__ float bf2f(unsigned short u) {
    union { float f; unsigned int i; } v;
    v.i = ((unsigned int)u) << 16;
    return v.f;
}
__device__ __forceinline__ unsigned short f2bf(float f) {
    union { float f; unsigned int i; } v;
    v.f = f;
    unsigned int u = v.i;
    u += 0x7FFFu + ((u >> 16) & 1u);   // RNE
    return (unsigned short)(u >> 16);
}
__device__ __forceinline__ float ldf(const void* p, int is_f32, long long i) {
    if (is_f32) return ((const float*)p)[i];
    return bf2f(((const unsigned short*)p)[i]);
}
__device__ __forceinline__ bf16x8 ld8(const unsigned short* p) {
    return *(const bf16x8*)p;
}

// ---- diagnostic marker ----
__global__ void k_marker(void* out, float val, int n) {
    int i = blockIdx.x * 256 + threadIdx.x;
    if (i < n) ((unsigned short*)out)[i] = f2bf(val);
}

// ---- zero deg + detect dtypes (proven) ----
__global__ void k_detect(const int* ei, const unsigned short* xprobe,
                         int* flags, int* deg) {
    int t = threadIdx.x;
    int gid = blockIdx.x * 256 + t;
    if (gid < NN) deg[gid] = 0;
    if (blockIdx.x == 0) {
        __shared__ int hi_or;
        __shared__ int wild_cnt;
        if (t == 0) { hi_or = 0; wild_cnt = 0; }
        __syncthreads();
        int acc = 0;
        for (int i = 0; i < 8; i++) acc |= ei[2 * (t + i * 256) + 1];
        if (acc) atomicOr(&hi_or, 1);
        int wild = 0;
        for (int i = 0; i < 2; i++) {
            unsigned short u = xprobe[t + i * 256];
            int e = (u >> 7) & 0xFF;
            if (e <= 0x30 || e >= 0xC0) wild++;
        }
        atomicAdd(&wild_cnt, wild);
        __syncthreads();
        if (t == 0) {
            flags[0] = hi_or ? 0 : 1;           // 1 => int64 edge_index
            flags[1] = (wild_cnt > 32) ? 1 : 0; // 1 => fp32 float tensors
        }
    }
}

// ---- one-time convert (x skipped when already bf16: identity round-trip) ----
#define CVT_X   6400000
#define CVT_W1  32768
#define CVT_CW  131072
#define CVT_W2  12288
#define CVT_TOT (CVT_X + CVT_W1 + CVT_CW + CVT_W2)

__global__ void k_convert(const void* x, const void* w1, const void* cw, const void* w2,
                          const int* flags,
                          unsigned short* xb, unsigned short* w1t,
                          unsigned short* cwt, unsigned short* w2t) {
    long long idx = (long long)blockIdx.x * 256 + threadIdx.x;
    if (idx >= CVT_TOT) return;
    int f32 = flags[1];
    if (idx < CVT_X) {
        if (!f32) return;                      // bf16 input: lin1 reads x directly
        xb[idx] = f2bf(ldf(x, 1, idx));
    } else if (idx < CVT_X + CVT_W1) {
        long long j = idx - CVT_X;
        int n = (int)(j >> 7), k = (int)(j & 127);
        w1t[j] = f2bf(ldf(w1, f32, (long long)k * HIDC + n));
    } else if (idx < CVT_X + CVT_W1 + CVT_CW) {
        long long j = idx - (CVT_X + CVT_W1);
        int lg = (int)(j >> 14);
        int rem = (int)(j & 16383);
        int n = rem >> 7, k = rem & 127;
        cwt[j] = f2bf(ldf(cw, f32, (long long)lg * GCH * GCH + (long long)k * GCH + n));
    } else {
        long long j = idx - (CVT_X + CVT_W1 + CVT_CW);
        int n = (int)(j >> 8), k = (int)(j & 255);
        w2t[j] = (n < OUTC) ? f2bf(ldf(w2, f32, (long long)k * OUTC + n)) : (unsigned short)0;
    }
}

__global__ void k_convert2(const void* b1, const void* ng, const void* nb, const void* cb,
                           const void* fg, const void* fb, const void* b2,
                           const int* flags,
                           float* b1f, float* ngf, float* nbf, float* cbf,
                           float* fgf, float* fbf, float* b2f) {
    int t = threadIdx.x;
    int f32 = flags[1];
    b1f[t] = ldf(b1, f32, t);
    fgf[t] = ldf(fg, f32, t);
    fbf[t] = ldf(fb, f32, t);
    if (t < 48) b2f[t] = (t < OUTC) ? ldf(b2, f32, t) : 0.0f;
    for (int i = 0; i < 4; i++) {
        int j = t + i * 256;
        ngf[j] = ldf(ng, f32, j);
        nbf[j] = ldf(nb, f32, j);
        cbf[j] = ldf(cb, f32, j);
    }
}

// ---- lin1: h = x @ W1 + b1 (h bf16; reads x directly when input is bf16) ----
__global__ __launch_bounds__(256) void k_lin1(
    const unsigned short* __restrict__ x_raw,
    const unsigned short* __restrict__ xb,
    const unsigned short* __restrict__ w1t,
    const float* __restrict__ b1f,
    const int* __restrict__ flags,
    unsigned short* __restrict__ h)
{
    const unsigned short* xs = flags[1] ? xb : x_raw;
    int bx = blockIdx.x;
    int r0 = (bx >> 1) * 128;
    int n0 = (bx & 1) * 128;
    int w = threadIdx.x >> 6, lane = threadIdx.x & 63;
    int quad = lane >> 4, ln = lane & 15;
    const f32x4 zf = {0.f, 0.f, 0.f, 0.f};
    const bf16x8 zb = {0, 0, 0, 0, 0, 0, 0, 0};
    f32x4 acc[2][8];
#pragma unroll
    for (int i = 0; i < 2; i++)
#pragma unroll
        for (int j = 0; j < 8; j++) acc[i][j] = zf;

#pragma unroll
    for (int kk = 0; kk < 4; kk++) {
        int ko = kk * 32 + quad * 8;
        bf16x8 a0, a1;
        {
            int r = r0 + w * 32 + ln;
            a0 = (r < NN) ? ld8(xs + (long long)r * INC + ko) : zb;
            r += 16;
            a1 = (r < NN) ? ld8(xs + (long long)r * INC + ko) : zb;
        }
#pragma unroll
        for (int nf = 0; nf < 8; nf++) {
            bf16x8 b = ld8(w1t + (long long)(n0 + nf * 16 + ln) * INC + ko);
            acc[0][nf] = __builtin_amdgcn_mfma_f32_16x16x32_bf16(a0, b, acc[0][nf], 0, 0, 0);
            acc[1][nf] = __builtin_amdgcn_mfma_f32_16x16x32_bf16(a1, b, acc[1][nf], 0, 0, 0);
        }
    }
#pragma unroll
    for (int mi = 0; mi < 2; mi++)
#pragma unroll
        for (int nf = 0; nf < 8; nf++) {
            int col = n0 + nf * 16 + ln;
            float bias = b1f[col];
#pragma unroll
            for (int r4 = 0; r4 < 4; r4++) {
                int row = r0 + w * 32 + mi * 16 + quad * 4 + r4;
                if (row < NN) h[(long long)row * HIDC + col] = f2bf(acc[mi][nf][r4] + bias);
            }
        }
}

// ---- fused LN+ReLU+GEMM (128-row tiles, h bf16) ----
#define TSTR 152
__global__ __launch_bounds__(256) void k_ln_gemm(
    const unsigned short* __restrict__ h,
    const unsigned short* __restrict__ cw,
    const float* __restrict__ ga,
    const float* __restrict__ be,
    int in_half,
    unsigned short* __restrict__ z)
{
    __shared__ __align__(16) unsigned short a_tile[128 * TSTR];
    int t = threadIdx.x;
    int r0 = blockIdx.x * 128;

    int row = t >> 1, hh = t & 1;
    int r = r0 + row;
    const unsigned short* hp = h + (long long)r * HIDC + in_half * GCH + hh * 64;

    float sum = 0.f, sq = 0.f;
    float vbuf[64];
    if (r < NN) {
#pragma unroll
        for (int i = 0; i < 8; i++) {
            u16x8 v = *(const u16x8*)(hp + i * 8);
#pragma unroll
            for (int j = 0; j < 8; j++) {
                float f = bf2f(v[j]);
                vbuf[i * 8 + j] = f;
                sum += f;
                sq += f * f;
            }
        }
    } else {
#pragma unroll
        for (int i = 0; i < 64; i++) vbuf[i] = 0.f;
    }
    sum += __shfl_xor(sum, 1, 64);
    sq  += __shfl_xor(sq, 1, 64);
    float mu = sum * (1.0f / GCH);
    float var = sq * (1.0f / GCH) - mu * mu;
    float rs = rsqrtf(var + EPSV);

#pragma unroll
    for (int i = 0; i < 16; i++) {
        int c = hh * 64 + i * 4;
        u16x4 o;
#pragma unroll
        for (int j = 0; j < 4; j++) {
            float val = (vbuf[i * 4 + j] - mu) * rs * ga[c + j] + be[c + j];
            if (val < 0.f) val = 0.f;
            o[j] = f2bf(val);
        }
        *(u16x4*)(&a_tile[row * TSTR + c]) = o;
    }
    __syncthreads();

    int w = t >> 6, lane = t & 63;
    int quad = lane >> 4, ln = lane & 15;
    const f32x4 zf = {0.f, 0.f, 0.f, 0.f};
    f32x4 acc[2][8];
#pragma unroll
    for (int i = 0; i < 2; i++)
#pragma unroll
        for (int j = 0; j < 8; j++) acc[i][j] = zf;

#pragma unroll
    for (int kk = 0; kk < 4; kk++) {
        int ko = kk * 32 + quad * 8;
        bf16x8 a0 = *(const bf16x8*)(&a_tile[(w * 32 + ln) * TSTR + ko]);
        bf16x8 a1 = *(const bf16x8*)(&a_tile[(w * 32 + 16 + ln) * TSTR + ko]);
#pragma unroll
        for (int nf = 0; nf < 8; nf++) {
            bf16x8 b = ld8(cw + (long long)(nf * 16 + ln) * GCH + ko);
            acc[0][nf] = __builtin_amdgcn_mfma_f32_16x16x32_bf16(a0, b, acc[0][nf], 0, 0, 0);
            acc[1][nf] = __builtin_amdgcn_mfma_f32_16x16x32_bf16(a1, b, acc[1][nf], 0, 0, 0);
        }
    }
#pragma unroll
    for (int mi = 0; mi < 2; mi++)
#pragma unroll
        for (int nf = 0; nf < 8; nf++) {
            int col = nf * 16 + ln;
#pragma unroll
            for (int r4 = 0; r4 < 4; r4++) {
                int row2 = r0 + w * 32 + mi * 16 + quad * 4 + r4;
                if (row2 < NN) z[(long long)row2 * GCH + col] = f2bf(acc[mi][nf][r4]);
            }
        }
}

// ---- CSR build ----
__global__ void k_count(const int* __restrict__ ei, const int* __restrict__ flags,
                        int* __restrict__ deg) {
    int e = (blockIdx.x * 256 + threadIdx.x) * 2;
    if (e >= NEDGE) return;
    int d0, d1;
    if (flags[0]) {
        int4 v = *(const int4*)(ei + 2 * (NEDGE + e));
        d0 = v.x; d1 = v.z;
    } else {
        int2 v = *(const int2*)(ei + NEDGE + e);
        d0 = v.x; d1 = v.y;
    }
    atomicAdd(&deg[d0], 1);
    if (e + 1 < NEDGE) atomicAdd(&deg[d1], 1);
}

#define SCAN_B 49
__global__ void k_scan_a(const int* __restrict__ deg, int* __restrict__ bsum) {
    __shared__ int part[256];
    int b = blockIdx.x, t = threadIdx.x;
    int base = b * 1024 + t * 4;
    int s = 0;
#pragma unroll
    for (int j = 0; j < 4; j++) {
        int i = base + j;
        if (i < NN) s += deg[i];
    }
    part[t] = s;
    __syncthreads();
    for (int off = 128; off > 0; off >>= 1) {
        if (t < off) part[t] += part[t + off];
        __syncthreads();
    }
    if (t == 0) bsum[b] = part[0];
}

__global__ void k_scan_b(const int* __restrict__ bsum, int* __restrict__ boff) {
    if (threadIdx.x == 0) {
        int run = 0;
        for (int i = 0; i < SCAN_B; i++) { boff[i] = run; run += bsum[i]; }
    }
}

__global__ void k_scan_c(const int* __restrict__ deg, const int* __restrict__ boff,
                         int* __restrict__ rowptr, int* __restrict__ cursor) {
    __shared__ int part[256];
    int b = blockIdx.x, t = threadIdx.x;
    int base = b * 1024 + t * 4;
    int v[4];
    int s = 0;
#pragma unroll
    for (int j = 0; j < 4; j++) {
        int i = base + j;
        v[j] = (i < NN) ? deg[i] : 0;
        s += v[j];
    }
    part[t] = s;
    __syncthreads();
    for (int off = 1; off < 256; off <<= 1) {
        int x = (t >= off) ? part[t - off] : 0;
        __syncthreads();
        part[t] += x;
        __syncthreads();
    }
    int run = boff[b] + part[t] - s;
#pragma unroll
    for (int j = 0; j < 4; j++) {
        int i = base + j;
        if (i < NN) { rowptr[i] = run; cursor[i] = run; }
        run += v[j];
    }
    if (b == SCAN_B - 1 && t == 255) rowptr[NN] = NEDGE;
}

// packed fill: ONE 4B store per edge — (bf16 weight << 16) | src (src < 65536)
__global__ void k_fill(const int* __restrict__ ei, const void* __restrict__ ew,
                       const int* __restrict__ flags,
                       int* __restrict__ cursor, unsigned int* __restrict__ epk) {
    int e = (blockIdx.x * 256 + threadIdx.x) * 2;
    if (e >= NEDGE) return;
    int is64 = flags[0];
    int f32 = flags[1];
    int d0, s0, d1 = 0, s1 = 0;
    int has1 = (e + 1 < NEDGE);
    if (is64) {
        d0 = ei[2 * (NEDGE + e)];
        s0 = ei[2 * e];
        if (has1) { d1 = ei[2 * (NEDGE + e) + 2]; s1 = ei[2 * e + 2]; }
    } else {
        d0 = ei[NEDGE + e];
        s0 = ei[e];
        if (has1) { d1 = ei[NEDGE + e + 1]; s1 = ei[e + 1]; }
    }
    int p0 = atomicAdd(&cursor[d0], 1);
    int p1 = has1 ? atomicAdd(&cursor[d1], 1) : 0;
    unsigned int w0 = f2bf(ldf(ew, f32, e));
    epk[p0] = (w0 << 16) | (unsigned int)s0;
    if (has1) {
        unsigned int w1 = f2bf(ldf(ew, f32, e + 1));
        epk[p1] = (w1 << 16) | (unsigned int)s1;
    }
}

// ---- aggregate: 16 thr/node x u16x8, 8-edge unroll, packed edges, h bf16 RMW ----
__global__ __launch_bounds__(256) void k_agg(
    const int* __restrict__ rowptr, const unsigned int* __restrict__ epk,
    const unsigned short* __restrict__ z,
    const float* __restrict__ cb,
    unsigned short* __restrict__ h, int out_half)
{
    int node = blockIdx.x * 16 + (threadIdx.x >> 4);
    if (node >= NN) return;
    int c8 = (threadIdx.x & 15) << 3;   // 8 channels/thread
    int beg = rowptr[node], end = rowptr[node + 1];
    const unsigned short* zb = z + c8;
    float acc[8];
#pragma unroll
    for (int j = 0; j < 8; j++) acc[j] = 0.f;

    int e = beg;
    for (; e + 7 < end; e += 8) {
        unsigned int pe[8];
        u16x8 v[8];
#pragma unroll
        for (int i = 0; i < 8; i++) pe[i] = epk[e + i];
#pragma unroll
        for (int i = 0; i < 8; i++)
            v[i] = *(const u16x8*)(zb + (long long)(pe[i] & 0xFFFFu) * GCH);
#pragma unroll
        for (int i = 0; i < 8; i++) {
            float w = bf2f((unsigned short)(pe[i] >> 16));
#pragma unroll
            for (int j = 0; j < 8; j++) acc[j] += w * bf2f(v[i][j]);
        }
    }
    if (e + 3 < end) {
        unsigned int pe[4];
        u16x8 v[4];
#pragma unroll
        for (int i = 0; i < 4; i++) pe[i] = epk[e + i];
#pragma unroll
        for (int i = 0; i < 4; i++)
            v[i] = *(const u16x8*)(zb + (long long)(pe[i] & 0xFFFFu) * GCH);
#pragma unroll
        for (int i = 0; i < 4; i++) {
            float w = bf2f((unsigned short)(pe[i] >> 16));
#pragma unroll
            for (int j = 0; j < 8; j++) acc[j] += w * bf2f(v[i][j]);
        }
        e += 4;
    }
    for (; e < end; e++) {
        unsigned int pe = epk[e];
        float w0 = bf2f((unsigned short)(pe >> 16));
        u16x8 v = *(const u16x8*)(zb + (long long)(pe & 0xFFFFu) * GCH);
#pragma unroll
        for (int j = 0; j < 8; j++) acc[j] += w0 * bf2f(v[j]);
    }

    unsigned short* hp = h + (long long)node * HIDC + out_half * GCH + c8;
    u16x8 hv = *(u16x8*)hp;
#pragma unroll
    for (int j = 0; j < 8; j++)
        hv[j] = f2bf(bf2f(hv[j]) + acc[j] + cb[c8 + j]);
    *(u16x8*)hp = hv;
}

// ---- final: out = relu(LN256(h)) @ W2 + b2 (h bf16) ----
#define FSTR 280
__global__ __launch_bounds__(256) void k_final(
    const unsigned short* __restrict__ h,
    const unsigned short* __restrict__ w2t,
    const float* __restrict__ fgf, const float* __restrict__ fbf,
    const float* __restrict__ b2f,
    const int* __restrict__ flags,
    void* __restrict__ out)
{
    __shared__ __align__(16) unsigned short a_tile[64 * FSTR];
    int t = threadIdx.x;
    int r0 = blockIdx.x * 64;

    int row = t >> 2, q = t & 3;
    int r = r0 + row;
    const unsigned short* hp = h + (long long)r * HIDC + q * 64;
    float sum = 0.f, sq = 0.f;
    float vbuf[64];
    if (r < NN) {
#pragma unroll
        for (int i = 0; i < 8; i++) {
            u16x8 v = *(const u16x8*)(hp + i * 8);
#pragma unroll
            for (int j = 0; j < 8; j++) {
                float f = bf2f(v[j]);
                vbuf[i * 8 + j] = f;
                sum += f;
                sq += f * f;
            }
        }
    } else {
#pragma unroll
        for (int i = 0; i < 64; i++) vbuf[i] = 0.f;
    }
    sum += __shfl_xor(sum, 1, 64);
    sum += __shfl_xor(sum, 2, 64);
    sq  += __shfl_xor(sq, 1, 64);
    sq  += __shfl_xor(sq, 2, 64);
    float mu = sum * (1.0f / HIDC);
    float var = sq * (1.0f / HIDC) - mu * mu;
    float rs = rsqrtf(var + EPSV);

#pragma unroll
    for (int i = 0; i < 16; i++) {
        int c = q * 64 + i * 4;
        u16x4 o;
#pragma unroll
        for (int j = 0; j < 4; j++) {
            float val = (vbuf[i * 4 + j] - mu) * rs * fgf[c + j] + fbf[c + j];
            if (val < 0.f) val = 0.f;
            o[j] = f2bf(val);
        }
        *(u16x4*)(&a_tile[row * FSTR + c]) = o;
    }
    __syncthreads();

    int w = t >> 6, lane = t & 63;
    int quad = lane >> 4, ln = lane & 15;
    const f32x4 zf = {0.f, 0.f, 0.f, 0.f};
    f32x4 acc[3];
#pragma unroll
    for (int j = 0; j < 3; j++) acc[j] = zf;
#pragma unroll
    for (int kk = 0; kk < 8; kk++) {
        int ko = kk * 32 + quad * 8;
        bf16x8 a = *(const bf16x8*)(&a_tile[(w * 16 + ln) * FSTR + ko]);
#pragma unroll
        for (int nf = 0; nf < 3; nf++) {
            bf16x8 b = ld8(w2t + (long long)(nf * 16 + ln) * HIDC + ko);
            acc[nf] = __builtin_amdgcn_mfma_f32_16x16x32_bf16(a, b, acc[nf], 0, 0, 0);
        }
    }
    int f32o = flags[1];
#pragma unroll
    for (int nf = 0; nf < 3; nf++) {
        int col = nf * 16 + ln;
        if (col >= OUTC) continue;
        float bias = b2f[col];
#pragma unroll
        for (int r4 = 0; r4 < 4; r4++) {
            int row2 = r0 + w * 16 + quad * 4 + r4;
            if (row2 < NN) {
                float val = acc[nf][r4] + bias;
                long long o = (long long)row2 * OUTC + col;
                if (f32o) ((float*)out)[o] = val;
                else      ((unsigned short*)out)[o] = f2bf(val);
            }
        }
    }
}

extern "C" void kernel_launch(void* const* d_in, const int* in_sizes, int n_in,
                              void* d_out, int out_size, void* d_ws, size_t ws_size,
                              hipStream_t stream)
{
    const void* x       = d_in[0];
    const int*  ei      = (const int*)d_in[1];
    const void* ew      = d_in[2];
    const void* lin1_w  = d_in[3];
    const void* lin1_b  = d_in[4];
    const void* lin2_w  = d_in[5];
    const void* lin2_b  = d_in[6];
    const void* norm_g  = d_in[7];
    const void* norm_b  = d_in[8];
    const void* conv_w  = d_in[9];
    const void* conv_b  = d_in[10];
    const void* fnorm_g = d_in[11];
    const void* fnorm_b = d_in[12];

    char* ws = (char*)d_ws;
    size_t off = 0;
    auto alloc = [&](size_t bytes) { void* p = (void*)(ws + off); off += (bytes + 255) & ~255ull; return p; };

    unsigned short* h      = (unsigned short*)alloc((size_t)NN * HIDC * 2);
    unsigned short* z      = (unsigned short*)alloc((size_t)NN * GCH * 2);
    unsigned short* xb     = (unsigned short*)alloc((size_t)NN * INC * 2);
    unsigned short* w1t    = (unsigned short*)alloc((size_t)CVT_W1 * 2);
    unsigned short* cwt    = (unsigned short*)alloc((size_t)CVT_CW * 2);
    unsigned short* w2t    = (unsigned short*)alloc((size_t)CVT_W2 * 2);
    float*          b1f    = (float*)alloc(256 * 4);
    float*          ngf    = (float*)alloc(1024 * 4);
    float*          nbf    = (float*)alloc(1024 * 4);
    float*          cbf    = (float*)alloc(1024 * 4);
    float*          fgf    = (float*)alloc(256 * 4);
    float*          fbf    = (float*)alloc(256 * 4);
    float*          b2f    = (float*)alloc(48 * 4);
    int*            deg    = (int*)alloc((size_t)NN * 4);
    int*            rowptr = (int*)alloc(((size_t)NN + 1) * 4);
    int*            cursor = (int*)alloc((size_t)NN * 4);
    unsigned int*   epk    = (unsigned int*)alloc((size_t)NEDGE * 4);
    int*            flags  = (int*)alloc(256);
    int*            bsum   = (int*)alloc(SCAN_B * 4);
    int*            boff   = (int*)alloc(SCAN_B * 4);

    if (ws_size < off || n_in < 13) {
        float mv = 100.0f + (float)(ws_size >> 20) + ((n_in < 13) ? 10000.0f : 0.0f);
        k_marker<<<(out_size + 255) / 256, 256, 0, stream>>>(d_out, mv, out_size);
        return;
    }

    k_detect<<<196, 256, 0, stream>>>(ei, (const unsigned short*)x, flags, deg);
    k_convert<<<(CVT_TOT + 255) / 256, 256, 0, stream>>>(x, lin1_w, conv_w, lin2_w,
                                                         flags, xb, w1t, cwt, w2t);
    k_convert2<<<1, 256, 0, stream>>>(lin1_b, norm_g, norm_b, conv_b,
                                      fnorm_g, fnorm_b, lin2_b, flags,
                                      b1f, ngf, nbf, cbf, fgf, fbf, b2f);
    k_lin1<<<782, 256, 0, stream>>>((const unsigned short*)x, xb, w1t, b1f, flags, h);

    k_count<<<(NEDGE / 2 + 255) / 256, 256, 0, stream>>>(ei, flags, deg);
    k_scan_a<<<SCAN_B, 256, 0, stream>>>(deg, bsum);
    k_scan_b<<<1, 64, 0, stream>>>(bsum, boff);
    k_scan_c<<<SCAN_B, 256, 0, stream>>>(deg, boff, rowptr, cursor);
    k_fill<<<(NEDGE / 2 + 255) / 256, 256, 0, stream>>>(ei, ew, flags, cursor, epk);

    const int AGG_B = (NN + 15) / 16;   // 3125
    for (int l = 0; l < NL; l++) {
        for (int g = 0; g < NG; g++) {
            int lg = l * NG + g;
            int in_half = g ^ 1;
            k_ln_gemm<<<391, 256, 0, stream>>>(h, cwt + (size_t)lg * GCH * GCH,
                                               ngf + lg * GCH, nbf + lg * GCH,
                                               in_half, z);
            k_agg<<<AGG_B, 256, 0, stream>>>(rowptr, epk, z,
                                             cbf + lg * GCH, h, g);
        }
    }
    k_final<<<782, 256, 0, stream>>>(h, w2t, fgf, fbf, b2f, flags, d_out);
}